// Round 1
// baseline (1588.781 us; speedup 1.0000x reference)
//
#include <hip/hip_runtime.h>
#include <hip/hip_bf16.h>
#include <math.h>

#define Q 9
#define G 8
#define NPIX (768 * 768)
#define HID 32
#define N_IN 6

// Fused-weight workspace layout (floats):
//   [0,1536)    W1g[g][k][j]  = sum_i Ainv[g][i][k] * W1[i][j]   (g*6+k)*32+j
//   [1536,2304) W3g[g][k][i]  = sum_j W3[k][j] * A[g][i][j]      (g*32+k)*3+i
//   [2304,2307) b3t[i]        = sum_g sum_j A[g][i][j] * b3[j]
#define W3G_OFF 1536
#define B3T_OFF 2304

__global__ void prep_fused_weights(const float* __restrict__ actions,
                                   const float* __restrict__ inv_actions,
                                   const float* __restrict__ W1,
                                   const float* __restrict__ W3,
                                   const float* __restrict__ b3,
                                   float* __restrict__ ws) {
    int t = threadIdx.x;
    // W1g: 1536 entries
    for (int idx = t; idx < G * N_IN * HID; idx += blockDim.x) {
        int j = idx & 31;
        int k = (idx >> 5) % N_IN;
        int g = idx / (N_IN * HID);
        float acc = 0.f;
        #pragma unroll
        for (int i = 0; i < N_IN; i++)
            acc += inv_actions[g * 81 + i * 9 + k] * W1[i * HID + j];
        ws[idx] = acc;
    }
    // W3g: 768 entries
    for (int idx = t; idx < G * HID * 3; idx += blockDim.x) {
        int i = idx % 3;
        int k = (idx / 3) & 31;
        int g = idx / (HID * 3);
        float acc = 0.f;
        #pragma unroll
        for (int j = 0; j < 3; j++)
            acc += W3[k * 3 + j] * actions[g * 81 + (6 + i) * 9 + (6 + j)];
        ws[W3G_OFF + idx] = acc;
    }
    // b3t: 3 entries
    if (t < 3) {
        float acc = 0.f;
        #pragma unroll
        for (int g = 0; g < G; g++)
            #pragma unroll
            for (int j = 0; j < 3; j++)
                acc += actions[g * 81 + (6 + t) * 9 + (6 + j)] * b3[j];
        ws[B3T_OFF + t] = acc;
    }
}

__global__ __launch_bounds__(256) void enc_kernel(
    const float* __restrict__ f,
    const float* __restrict__ M,
    const float* __restrict__ Minv,
    const float* __restrict__ e,
    const float* __restrict__ w,
    const float* __restrict__ b1,
    const float* __restrict__ W2,
    const float* __restrict__ b2,
    const float* __restrict__ fused,
    float* __restrict__ out) {
    const int p = blockIdx.x * blockDim.x + threadIdx.x;  // exact cover: 2304*256

    // ---- load f and compute moments m = M @ f ----
    float fv[Q];
    #pragma unroll
    for (int q = 0; q < Q; q++) fv[q] = f[q * NPIX + p];
    float m[Q];
    #pragma unroll
    for (int q = 0; q < Q; q++) {
        float acc = 0.f;
        #pragma unroll
        for (int pp = 0; pp < Q; pp++) acc = fmaf(M[q * 9 + pp], fv[pp], acc);
        m[q] = acc;
    }

    // ---- 8x fused MLP, accumulate group-combined output ----
    float out3[3] = {fused[B3T_OFF + 0], fused[B3T_OFF + 1], fused[B3T_OFF + 2]};
    #pragma unroll 1
    for (int g = 0; g < G; g++) {
        float h1[HID];
        #pragma unroll
        for (int j = 0; j < HID; j++) h1[j] = b1[j];
        const float* w1p = fused + g * N_IN * HID;
        #pragma unroll
        for (int k = 0; k < N_IN; k++) {
            float a = m[k];
            #pragma unroll
            for (int j = 0; j < HID; j++) h1[j] = fmaf(a, w1p[k * HID + j], h1[j]);
        }
        #pragma unroll
        for (int j = 0; j < HID; j++) h1[j] = fmaxf(h1[j], 0.f);

        float h2[HID];
        #pragma unroll
        for (int j = 0; j < HID; j++) h2[j] = b2[j];
        #pragma unroll
        for (int i = 0; i < HID; i++) {
            float a = h1[i];
            #pragma unroll
            for (int j = 0; j < HID; j++) h2[j] = fmaf(a, W2[i * HID + j], h2[j]);
        }
        #pragma unroll
        for (int k = 0; k < HID; k++) h2[k] = fmaxf(h2[k], 0.f);

        const float* w3p = fused + W3G_OFF + g * HID * 3;
        #pragma unroll
        for (int k = 0; k < HID; k++) {
            float a = h2[k];
            out3[0] = fmaf(a, w3p[k * 3 + 0], out3[0]);
            out3[1] = fmaf(a, w3p[k * 3 + 1], out3[1]);
            out3[2] = fmaf(a, w3p[k * 3 + 2], out3[2]);
        }
    }

    // ---- tau (elu) ----
    float tau_inv[Q];
    #pragma unroll
    for (int q = 0; q < N_IN; q++) tau_inv[q] = 1.25f;  // 1/0.8
    #pragma unroll
    for (int i = 0; i < 3; i++) {
        float o = out3[i];
        float el = o > 0.f ? o : (expf(o) - 1.f);
        tau_inv[N_IN + i] = 1.f / (1.5f + el);
    }

    // ---- equilibrium ----
    float rho = m[0];
    float invr = 1.f / rho;
    float u0 = m[1] * invr, u1 = m[2] * invr;
    float usq = u0 * u0 + u1 * u1;
    float feq[Q];
    #pragma unroll
    for (int q = 0; q < Q; q++) {
        float eu = e[2 * q] * u0 + e[2 * q + 1] * u1;
        feq[q] = w[q] * rho * (1.f + 3.f * eu + 4.5f * eu * eu - 1.5f * usq);
    }

    // ---- relax in moment space, map back with Minv ----
    float mpost[Q];
    #pragma unroll
    for (int q = 0; q < Q; q++) {
        float acc = 0.f;
        #pragma unroll
        for (int pp = 0; pp < Q; pp++) acc = fmaf(M[q * 9 + pp], feq[pp], acc);
        mpost[q] = m[q] - (m[q] - acc) * tau_inv[q];
    }
    #pragma unroll
    for (int q = 0; q < Q; q++) {
        float acc = 0.f;
        #pragma unroll
        for (int pp = 0; pp < Q; pp++) acc = fmaf(Minv[q * 9 + pp], mpost[pp], acc);
        out[q * NPIX + p] = acc;
    }
}

extern "C" void kernel_launch(void* const* d_in, const int* in_sizes, int n_in,
                              void* d_out, int out_size, void* d_ws, size_t ws_size,
                              hipStream_t stream) {
    const float* f           = (const float*)d_in[0];
    const float* M           = (const float*)d_in[1];
    const float* Minv        = (const float*)d_in[2];
    const float* actions     = (const float*)d_in[3];
    const float* inv_actions = (const float*)d_in[4];
    const float* e           = (const float*)d_in[5];
    const float* w           = (const float*)d_in[6];
    const float* W1          = (const float*)d_in[7];
    const float* b1          = (const float*)d_in[8];
    const float* W2          = (const float*)d_in[9];
    const float* b2          = (const float*)d_in[10];
    const float* W3          = (const float*)d_in[11];
    const float* b3          = (const float*)d_in[12];
    float* out = (float*)d_out;
    float* ws  = (float*)d_ws;

    prep_fused_weights<<<1, 256, 0, stream>>>(actions, inv_actions, W1, W3, b3, ws);
    enc_kernel<<<NPIX / 256, 256, 0, stream>>>(f, M, Minv, e, w, b1, W2, b2, ws, out);
}

// Round 2
// 195.565 us; speedup vs baseline: 8.1240x; 8.1240x over previous
//
#include <hip/hip_runtime.h>
#include <math.h>

#define Q 9
#define G 8
#define NPIX (768 * 768)
#define HID 32
#define N_IN 6

// ws layout: shorts [0,8192): W1 frags (16 c-tiles)
//            shorts [8192,9216): W2 frags (2 n-tiles)
//            shorts [9216,13312): W3 frags (8 groups)
//            floats at float-index [6656,6659): b3t
#define W2F_OFF 8192
#define W3F_OFF 9216
#define B3T_F_OFF 6656

typedef short bf16x8 __attribute__((ext_vector_type(8)));
typedef float f32x4 __attribute__((ext_vector_type(4)));

__device__ __forceinline__ unsigned short f2bf(float x) {
    unsigned u = __builtin_bit_cast(unsigned, x);
    unsigned r = u + 0x7FFFu + ((u >> 16) & 1u);
    return (unsigned short)(r >> 16);
}

// Pack fused weights into per-lane MFMA B-fragment order (bf16).
// B-frag layout for mfma_f32_16x16x32_bf16: lane l holds B[k=(l>>4)*8+j][n=(l&15)], j=0..7.
__global__ void prep_fused_weights(const float* __restrict__ actions,
                                   const float* __restrict__ inv_actions,
                                   const float* __restrict__ W1,
                                   const float* __restrict__ W2,
                                   const float* __restrict__ W3,
                                   const float* __restrict__ b3,
                                   short* __restrict__ wsb,
                                   float* __restrict__ wsf) {
    int t = threadIdx.x;
    // Layer-1 B frags: 16 col-tiles of W1cat[k][n], n = g*32+jj, k<6 else 0.
    for (int idx = t; idx < 16 * 64 * 8; idx += blockDim.x) {
        int j = idx & 7;
        int l = (idx >> 3) & 63;
        int c = idx >> 9;
        int n = c * 16 + (l & 15);
        int g = n >> 5, jj = n & 31;
        int k = ((l >> 4) << 3) + j;
        float v = 0.f;
        if (k < N_IN) {
            for (int i = 0; i < N_IN; i++)
                v += inv_actions[g * 81 + i * 9 + k] * W1[i * HID + jj];
        }
        wsb[idx] = (short)f2bf(v);
    }
    // Layer-2 B frags: W2[k][n], 2 n-tiles.
    for (int idx = t; idx < 2 * 64 * 8; idx += blockDim.x) {
        int j = idx & 7;
        int l = (idx >> 3) & 63;
        int u = idx >> 9;
        int n = u * 16 + (l & 15);
        int k = ((l >> 4) << 3) + j;
        wsb[W2F_OFF + idx] = (short)f2bf(W2[k * HID + n]);
    }
    // Layer-3 B frags: W3g[g][k][n] = sum_j3 W3[k][j3]*A[g][6+n][6+j3], n<3 else 0.
    for (int idx = t; idx < 8 * 64 * 8; idx += blockDim.x) {
        int j = idx & 7;
        int l = (idx >> 3) & 63;
        int g = idx >> 9;
        int n = l & 15;
        int k = ((l >> 4) << 3) + j;
        float v = 0.f;
        if (n < 3) {
            for (int j3 = 0; j3 < 3; j3++)
                v += W3[k * 3 + j3] * actions[g * 81 + (6 + n) * 9 + (6 + j3)];
        }
        wsb[W3F_OFF + idx] = (short)f2bf(v);
    }
    // b3t
    if (t < 3) {
        float acc = 0.f;
        for (int g = 0; g < G; g++)
            for (int j = 0; j < 3; j++)
                acc += actions[g * 81 + (6 + t) * 9 + (6 + j)] * b3[j];
        wsf[B3T_F_OFF + t] = acc;
    }
}

#define LW 40  // padded h row length in shorts (80 B, 16B-aligned, 2-way banks)

__global__ __launch_bounds__(256, 3) void lbm_mfma_kernel(
    const float* __restrict__ f,
    const float* __restrict__ M,
    const float* __restrict__ Minv,
    const float* __restrict__ e,
    const float* __restrict__ w,
    const float* __restrict__ b1,
    const float* __restrict__ b2,
    const short* __restrict__ wsb,
    const float* __restrict__ wsf,
    float* __restrict__ out) {
    __shared__ __align__(16) short xinL[4][32][32];
    __shared__ __align__(16) short h1L[4][64][LW];
    __shared__ __align__(16) short h2L[4][64][LW];
    __shared__ float o3L[4][32][4];

    const int tid = threadIdx.x;
    const int wv = tid >> 6;
    const int l = tid & 63;
    const int l15 = l & 15;
    const int quad = l >> 4;
    const int pbase = blockIdx.x * 128 + wv * 32;

    float m[Q];
    #pragma unroll
    for (int q = 0; q < Q; q++) m[q] = 0.f;

    // ---- phase A: moments (lanes 0..31, one pixel each) + stage x_in to LDS ----
    if (l < 32) {
        const int p = pbase + l;
        float fv[Q];
        #pragma unroll
        for (int q = 0; q < Q; q++) fv[q] = f[q * NPIX + p];
        #pragma unroll
        for (int q = 0; q < Q; q++) {
            float acc = 0.f;
            #pragma unroll
            for (int pp = 0; pp < Q; pp++) acc = fmaf(M[q * 9 + pp], fv[pp], acc);
            m[q] = acc;
        }
        int w0 = (int)f2bf(m[0]) | ((int)f2bf(m[1]) << 16);
        int w1 = (int)f2bf(m[2]) | ((int)f2bf(m[3]) << 16);
        int w2 = (int)f2bf(m[4]) | ((int)f2bf(m[5]) << 16);
        int4* row = (int4*)&xinL[wv][l][0];
        row[0] = make_int4(w0, w1, w2, 0);
        row[1] = make_int4(0, 0, 0, 0);
        row[2] = make_int4(0, 0, 0, 0);
        row[3] = make_int4(0, 0, 0, 0);
    }
    __syncthreads();

    // ---- resident fragments ----
    bf16x8 a1[2];
    #pragma unroll
    for (int t = 0; t < 2; t++)
        a1[t] = *(const bf16x8*)&xinL[wv][t * 16 + l15][quad * 8];
    bf16x8 w2f[2];
    #pragma unroll
    for (int u = 0; u < 2; u++)
        w2f[u] = *(const bf16x8*)&wsb[W2F_OFF + (u * 64 + l) * 8];
    bf16x8 w3f[G];
    #pragma unroll
    for (int g = 0; g < G; g++)
        w3f[g] = *(const bf16x8*)&wsb[W3F_OFF + (g * 64 + l) * 8];
    const float b1a = b1[l15], b1b = b1[16 + l15];
    const float b2a = b2[l15], b2b = b2[16 + l15];

    f32x4 oacc[2];
    oacc[0] = (f32x4){0.f, 0.f, 0.f, 0.f};
    oacc[1] = (f32x4){0.f, 0.f, 0.f, 0.f};

    // ---- 4 passes over groups (2 groups per pass) ----
    #pragma unroll 1
    for (int pass = 0; pass < 4; pass++) {
        // layer 1: 4 col-tiles (2 groups x 32 cols)
        #pragma unroll
        for (int ct = 0; ct < 4; ct++) {
            const int c = pass * 4 + ct;
            bf16x8 bfrag = *(const bf16x8*)&wsb[(c * 64 + l) * 8];
            const float bias = (ct & 1) ? b1b : b1a;
            const int j = ((ct & 1) << 4) + l15;
            #pragma unroll
            for (int t = 0; t < 2; t++) {
                f32x4 acc = (f32x4){0.f, 0.f, 0.f, 0.f};
                acc = __builtin_amdgcn_mfma_f32_16x16x32_bf16(a1[t], bfrag, acc, 0, 0, 0);
                const int ridb = ((ct >> 1) << 5) + t * 16 + (quad << 2);
                #pragma unroll
                for (int r = 0; r < 4; r++) {
                    float v = fmaxf(acc[r] + bias, 0.f);
                    h1L[wv][ridb + r][j] = (short)f2bf(v);
                }
            }
        }
        __syncthreads();
        // layer 2: 4 row-tiles x 2 n-tiles
        #pragma unroll
        for (int rt = 0; rt < 4; rt++) {
            bf16x8 afr = *(const bf16x8*)&h1L[wv][rt * 16 + l15][quad * 8];
            #pragma unroll
            for (int u = 0; u < 2; u++) {
                f32x4 acc = (f32x4){0.f, 0.f, 0.f, 0.f};
                acc = __builtin_amdgcn_mfma_f32_16x16x32_bf16(afr, w2f[u], acc, 0, 0, 0);
                const float bias = u ? b2b : b2a;
                const int rowb = rt * 16 + (quad << 2);
                const int n = (u << 4) + l15;
                #pragma unroll
                for (int r = 0; r < 4; r++) {
                    float v = fmaxf(acc[r] + bias, 0.f);
                    h2L[wv][rowb + r][n] = (short)f2bf(v);
                }
            }
        }
        __syncthreads();
        // layer 3: 4 row-tiles, accumulate over groups in C
        #pragma unroll
        for (int rt = 0; rt < 4; rt++) {
            bf16x8 afr = *(const bf16x8*)&h2L[wv][rt * 16 + l15][quad * 8];
            const int g = pass * 2 + (rt >> 1);
            oacc[rt & 1] = __builtin_amdgcn_mfma_f32_16x16x32_bf16(afr, w3f[g], oacc[rt & 1], 0, 0, 0);
        }
        __syncthreads();
    }

    // ---- scatter o (cols 0..2 hold outputs) ----
    if (l15 < 3) {
        #pragma unroll
        for (int h = 0; h < 2; h++)
            #pragma unroll
            for (int r = 0; r < 4; r++)
                o3L[wv][h * 16 + (quad << 2) + r][l15] = oacc[h][r];
    }
    __syncthreads();

    // ---- tail (lanes 0..31) ----
    if (l < 32) {
        const int p = pbase + l;
        float o0 = o3L[wv][l][0] + wsf[B3T_F_OFF + 0];
        float o1 = o3L[wv][l][1] + wsf[B3T_F_OFF + 1];
        float o2 = o3L[wv][l][2] + wsf[B3T_F_OFF + 2];

        float tau_inv[Q];
        #pragma unroll
        for (int q = 0; q < N_IN; q++) tau_inv[q] = 1.25f;
        float o3v[3] = {o0, o1, o2};
        #pragma unroll
        for (int i = 0; i < 3; i++) {
            float o = o3v[i];
            float el = o > 0.f ? o : (expf(o) - 1.f);
            tau_inv[N_IN + i] = 1.f / (1.5f + el);
        }

        const float rho = m[0];
        const float invr = 1.f / rho;
        const float u0 = m[1] * invr, u1 = m[2] * invr;
        const float usq = u0 * u0 + u1 * u1;
        float feq[Q];
        #pragma unroll
        for (int q = 0; q < Q; q++) {
            float eu = e[2 * q] * u0 + e[2 * q + 1] * u1;
            feq[q] = w[q] * rho * (1.f + 3.f * eu + 4.5f * eu * eu - 1.5f * usq);
        }
        float mpost[Q];
        #pragma unroll
        for (int q = 0; q < Q; q++) {
            float acc = 0.f;
            #pragma unroll
            for (int pp = 0; pp < Q; pp++) acc = fmaf(M[q * 9 + pp], feq[pp], acc);
            mpost[q] = m[q] - (m[q] - acc) * tau_inv[q];
        }
        #pragma unroll
        for (int q = 0; q < Q; q++) {
            float acc = 0.f;
            #pragma unroll
            for (int pp = 0; pp < Q; pp++) acc = fmaf(Minv[q * 9 + pp], mpost[pp], acc);
            out[q * NPIX + p] = acc;
        }
    }
}

extern "C" void kernel_launch(void* const* d_in, const int* in_sizes, int n_in,
                              void* d_out, int out_size, void* d_ws, size_t ws_size,
                              hipStream_t stream) {
    const float* f           = (const float*)d_in[0];
    const float* M           = (const float*)d_in[1];
    const float* Minv        = (const float*)d_in[2];
    const float* actions     = (const float*)d_in[3];
    const float* inv_actions = (const float*)d_in[4];
    const float* e           = (const float*)d_in[5];
    const float* w           = (const float*)d_in[6];
    const float* W1          = (const float*)d_in[7];
    const float* b1          = (const float*)d_in[8];
    const float* W2          = (const float*)d_in[9];
    const float* b2          = (const float*)d_in[10];
    const float* W3          = (const float*)d_in[11];
    const float* b3          = (const float*)d_in[12];
    float* out = (float*)d_out;
    short* wsb = (short*)d_ws;
    float* wsf = (float*)d_ws;

    prep_fused_weights<<<1, 256, 0, stream>>>(actions, inv_actions, W1, W2, W3, b3, wsb, wsf);
    lbm_mfma_kernel<<<NPIX / 128, 256, 0, stream>>>(f, M, Minv, e, w, b1, b2, wsb, wsf, out);
}

// Round 5
// 146.968 us; speedup vs baseline: 10.8104x; 1.3307x over previous
//
#include <hip/hip_runtime.h>
#include <math.h>

#define Q 9
#define NPIX (768 * 768)

typedef short bf16x8 __attribute__((ext_vector_type(8)));
typedef float f32x4 __attribute__((ext_vector_type(4)));
typedef int i32x4 __attribute__((ext_vector_type(4)));

// ws layout (shorts):
//   [0,4096)      A1a frags: 8 groups x 512   (W1e, m-half A, feature phiA(m)=8*(m>>2)+(m&3))
//   [4096,8192)   A1b frags: 8 groups x 512   (m-half B, phiB = phiA+4)
//   [8192,12288)  A3 frags:  8 groups x 512   (W3e, rows 0..2 used)
//   [12288,13312) A2a,A2b frags (W2)
// ws floats: b3t at float idx [6656,6659)
#define A1BV 512    // bf16x8-vector indices
#define A3V  1024
#define A2V  1536
#define B3TF 6656

__device__ __forceinline__ unsigned short f2bf(float x) {  // RTNE (prep only)
    unsigned u = __builtin_bit_cast(unsigned, x);
    unsigned r = u + 0x7FFFu + ((u >> 16) & 1u);
    return (unsigned short)(r >> 16);
}

// pack two f32 -> dword of two bf16 (round-to-nearest, ties away), first arg in LOW half
__device__ __forceinline__ unsigned packrnd(float e, float o) {
    unsigned ue = __builtin_bit_cast(unsigned, e) + 0x8000u;
    unsigned uo = __builtin_bit_cast(unsigned, o) + 0x8000u;
    return (uo & 0xFFFF0000u) | (ue >> 16);
}

__device__ __forceinline__ bf16x8 mk8(unsigned w0, unsigned w1, unsigned w2, unsigned w3) {
    i32x4 t = {(int)w0, (int)w1, (int)w2, (int)w3};
    return __builtin_bit_cast(bf16x8, t);
}

// ---- prep: pack fused weights into per-lane 16x16x32 A-fragment order ----
// A-frag layout (HW-proven in R2): lane l holds A[m=l&15][k=(l>>4)*8+j], j=0..7.
__global__ void prep_kernel(const float* __restrict__ actions,
                            const float* __restrict__ inv_actions,
                            const float* __restrict__ W1,
                            const float* __restrict__ b1,
                            const float* __restrict__ W2,
                            const float* __restrict__ W3,
                            const float* __restrict__ b3,
                            short* __restrict__ wsb,
                            float* __restrict__ wsf) {
    const int t = threadIdx.x;
    // A1a / A1b: W1e[g][k][feat]; k<6: sum_i Ainv[g,i,k]*W1[i,feat]; k==6: b1[feat]; else 0
    for (int idx = t; idx < 8192; idx += 256) {
        int j = idx & 7, l = (idx >> 3) & 63, g = (idx >> 9) & 7, half = idx >> 12;
        int m = l & 15, quad = l >> 4, k = quad * 8 + j;
        int feat = 8 * (m >> 2) + (m & 3) + 4 * half;
        float v = 0.f;
        if (k < 6) {
            for (int i = 0; i < 6; i++)
                v += inv_actions[g * 81 + i * 9 + k] * W1[i * 32 + feat];
        } else if (k == 6) v = b1[feat];
        wsb[idx] = (short)f2bf(v);
    }
    // A3: W3e[g][k][m] = sum_j3 W3[k,j3]*A[g,6+m,6+j3], m<3 else 0 (k = natural h2 label)
    for (int idx = t; idx < 4096; idx += 256) {
        int j = idx & 7, l = (idx >> 3) & 63, g = idx >> 9;
        int m = l & 15, quad = l >> 4, k = quad * 8 + j;
        float v = 0.f;
        if (m < 3)
            for (int j3 = 0; j3 < 3; j3++)
                v += W3[k * 3 + j3] * actions[g * 81 + (6 + m) * 9 + (6 + j3)];
        wsb[8192 + idx] = (short)f2bf(v);
    }
    // A2a / A2b: W2[k][feat], k = natural h1 label
    for (int idx = t; idx < 1024; idx += 256) {
        int j = idx & 7, l = (idx >> 3) & 63, half = idx >> 9;
        int m = l & 15, quad = l >> 4, k = quad * 8 + j;
        int feat = 8 * (m >> 2) + (m & 3) + 4 * half;
        wsb[12288 + idx] = (short)f2bf(W2[k * 32 + feat]);
    }
    if (t < 3) {
        float acc = 0.f;
        for (int g = 0; g < 8; g++)
            for (int j = 0; j < 3; j++)
                acc += actions[g * 81 + (6 + t) * 9 + (6 + j)] * b3[j];
        wsf[B3TF + t] = acc;
    }
}

__global__ __launch_bounds__(256, 4) void lbm_kernel(
    const float* __restrict__ f,
    const float* __restrict__ Minv,
    const float* __restrict__ w,
    const float* __restrict__ b2,
    const short* __restrict__ wsb,
    const float* __restrict__ wsf,
    float* __restrict__ out) {
    __shared__ float oL[4][64][4];

    const int tid = threadIdx.x;
    const int wv = tid >> 6;
    const int l = tid & 63;
    const int quad = l >> 4;
    const int lc = l & 15;
    const int p = blockIdx.x * 256 + tid;  // one pixel per lane

    // ---- load f, moments via {0,+-1} structure of M (19 adds) ----
    float fv0 = f[0 * NPIX + p], fv1 = f[1 * NPIX + p], fv2 = f[2 * NPIX + p];
    float fv3 = f[3 * NPIX + p], fv4 = f[4 * NPIX + p], fv5 = f[5 * NPIX + p];
    float fv6 = f[6 * NPIX + p], fv7 = f[7 * NPIX + p], fv8 = f[8 * NPIX + p];
    float sa = fv5 + fv6, sb = fv7 + fv8, sc = fv5 - fv6, sd = fv7 - fv8;
    float sab = sa + sb;
    float m8 = sab, m6 = sa - sb, m4 = sc + sd, m7 = sc - sd;
    float p13 = fv1 + fv3, d13 = fv1 - fv3, p24 = fv2 + fv4, d24 = fv2 - fv4;
    float m0 = fv0 + p13 + p24 + sab;
    float m1 = d13 + m7;
    float m2 = d24 + m6;
    float m3 = p13 + sab;
    float m5 = p24 + sab;

    // ---- B1 frags: broadcast moments of pixels nb*16..nb*16+15 to all quads ----
    unsigned mp0 = packrnd(m0, m1), mp1 = packrnd(m2, m3), mp2 = packrnd(m4, m5);
    const unsigned CONE = 0x00003F80u;  // (bf16 1.0 at k=6, 0 at k=7)
    bf16x8 B1[4];
    #pragma unroll
    for (int nb = 0; nb < 4; nb++) {
        int src = ((nb << 4) | lc) << 2;
        unsigned a = (unsigned)__builtin_amdgcn_ds_bpermute(src, (int)mp0);
        unsigned b = (unsigned)__builtin_amdgcn_ds_bpermute(src, (int)mp1);
        unsigned c = (unsigned)__builtin_amdgcn_ds_bpermute(src, (int)mp2);
        B1[nb] = mk8(a, b, c, CONE);  // only quad-0 rows (k=0..7) have nonzero A1
    }

    // ---- resident weights ----
    const bf16x8* wsv = (const bf16x8*)wsb;
    bf16x8 a2a = wsv[A2V + l], a2b = wsv[A2V + 64 + l];
    f32x4 c2iA = *(const f32x4*)(b2 + 8 * quad);       // bias of features 8q..8q+3
    f32x4 c2iB = *(const f32x4*)(b2 + 8 * quad + 4);   // features 8q+4..8q+7
    float b30 = wsf[B3TF + 0], b31 = wsf[B3TF + 1], b32 = wsf[B3TF + 2];
    f32x4 oinit;
    oinit[0] = (quad == 0) ? b30 : 0.f;
    oinit[1] = (quad == 0) ? b31 : 0.f;
    oinit[2] = (quad == 0) ? b32 : 0.f;
    oinit[3] = 0.f;
    f32x4 oacc[4] = {oinit, oinit, oinit, oinit};

    bf16x8 a1a = wsv[l], a1b = wsv[A1BV + l], a3 = wsv[A3V + l];

    #pragma unroll 1
    for (int g = 0; g < 8; g++) {
        const int gn = (g + 1) & 7;  // cyclic prefetch (g=7 result unused)
        bf16x8 na1a = wsv[gn * 64 + l];
        bf16x8 na1b = wsv[A1BV + gn * 64 + l];
        bf16x8 na3  = wsv[A3V + gn * 64 + l];
        #pragma unroll
        for (int nb = 0; nb < 4; nb++) {
            f32x4 z = {0.f, 0.f, 0.f, 0.f};
            // layer 1: feature phiA(4q+r)=8q+r in c1a[r], phiB -> 8q+4+r in c1b[r]
            f32x4 c1a = __builtin_amdgcn_mfma_f32_16x16x32_bf16(a1a, B1[nb], z, 0, 0, 0);
            f32x4 c1b = __builtin_amdgcn_mfma_f32_16x16x32_bf16(a1b, B1[nb], z, 0, 0, 0);
            // purely lane-local C->B transform: quad q holds exactly k=8q..8q+7
            bf16x8 B2 = mk8(
                packrnd(fmaxf(c1a[0], 0.f), fmaxf(c1a[1], 0.f)),
                packrnd(fmaxf(c1a[2], 0.f), fmaxf(c1a[3], 0.f)),
                packrnd(fmaxf(c1b[0], 0.f), fmaxf(c1b[1], 0.f)),
                packrnd(fmaxf(c1b[2], 0.f), fmaxf(c1b[3], 0.f)));
            // layer 2 (bias via C-input)
            f32x4 c2a = __builtin_amdgcn_mfma_f32_16x16x32_bf16(a2a, B2, c2iA, 0, 0, 0);
            f32x4 c2b = __builtin_amdgcn_mfma_f32_16x16x32_bf16(a2b, B2, c2iB, 0, 0, 0);
            bf16x8 B3 = mk8(
                packrnd(fmaxf(c2a[0], 0.f), fmaxf(c2a[1], 0.f)),
                packrnd(fmaxf(c2a[2], 0.f), fmaxf(c2a[3], 0.f)),
                packrnd(fmaxf(c2b[0], 0.f), fmaxf(c2b[1], 0.f)),
                packrnd(fmaxf(c2b[2], 0.f), fmaxf(c2b[3], 0.f)));
            // layer 3: accumulate over groups in C (rows 0..2 = output components)
            oacc[nb] = __builtin_amdgcn_mfma_f32_16x16x32_bf16(a3, B3, oacc[nb], 0, 0, 0);
        }
        a1a = na1a; a1b = na1b; a3 = na3;
    }

    // ---- collect outputs: quad-0 lanes hold rows 0..3 (components) of cols 0..15 ----
    if (quad == 0) {
        #pragma unroll
        for (int nb = 0; nb < 4; nb++)
            *(f32x4*)&oL[wv][nb * 16 + lc][0] = oacc[nb];
    }
    // wave-local LDS RAW: in-order per wave, lgkmcnt wait inserted by compiler; no barrier
    f32x4 ov = *(const f32x4*)&oL[wv][l][0];
    float o_[3] = {ov[0], ov[1], ov[2]};  // b3t already folded into oacc init

    // ---- tau ----
    float tinv[3];
    #pragma unroll
    for (int i = 0; i < 3; i++) {
        float o = o_[i];
        float el = (o > 0.f) ? o : (__expf(o) - 1.f);
        tinv[i] = 1.f / (1.5f + el);
    }

    // ---- equilibrium (structured) ----
    float rho = m0;
    float ir = 1.f / rho;
    float ux = m1 * ir, uy = m2 * ir;
    float usq = ux * ux + uy * uy;
    float base = 1.f - 1.5f * usq;
    float w0r = w[0] * rho, w1r = w[1] * rho, w5r = w[5] * rho;
    float feq0 = w0r * base;
    float ax = 4.5f * ux * ux + base, bx = 3.f * ux;
    float feq1 = w1r * (ax + bx), feq3 = w1r * (ax - bx);
    float ay = 4.5f * uy * uy + base, by = 3.f * uy;
    float feq2 = w1r * (ay + by), feq4 = w1r * (ay - by);
    float ss = ux + uy, as_ = 4.5f * ss * ss + base, bs = 3.f * ss;
    float feq5 = w5r * (as_ + bs), feq7 = w5r * (as_ - bs);
    float dd = uy - ux, ad = 4.5f * dd * dd + base, bd = 3.f * dd;
    float feq6 = w5r * (ad + bd), feq8 = w5r * (ad - bd);

    // meq = M @ feq (same 19-add structure)
    float ea = feq5 + feq6, eb = feq7 + feq8, ec = feq5 - feq6, ed = feq7 - feq8;
    float eab = ea + eb;
    float q8 = eab, q6 = ea - eb, q4 = ec + ed, q7 = ec - ed;
    float ep13 = feq1 + feq3, ed13 = feq1 - feq3, ep24 = feq2 + feq4, ed24 = feq2 - feq4;
    float q0 = feq0 + ep13 + ep24 + eab;
    float q1 = ed13 + q7, q2 = ed24 + q6, q3 = ep13 + eab, q5 = ep24 + eab;

    // relax
    float mp_[9];
    mp_[0] = m0 - (m0 - q0) * 1.25f;
    mp_[1] = m1 - (m1 - q1) * 1.25f;
    mp_[2] = m2 - (m2 - q2) * 1.25f;
    mp_[3] = m3 - (m3 - q3) * 1.25f;
    mp_[4] = m4 - (m4 - q4) * 1.25f;
    mp_[5] = m5 - (m5 - q5) * 1.25f;
    mp_[6] = m6 - (m6 - q6) * tinv[0];
    mp_[7] = m7 - (m7 - q7) * tinv[1];
    mp_[8] = m8 - (m8 - q8) * tinv[2];

    // out = Minv @ m_post (wave-uniform Minv -> scalar loads)
    #pragma unroll
    for (int q = 0; q < 9; q++) {
        float acc = Minv[q * 9 + 0] * mp_[0];
        #pragma unroll
        for (int pp = 1; pp < 9; pp++) acc = fmaf(Minv[q * 9 + pp], mp_[pp], acc);
        __builtin_nontemporal_store(acc, &out[q * NPIX + p]);
    }
}

extern "C" void kernel_launch(void* const* d_in, const int* in_sizes, int n_in,
                              void* d_out, int out_size, void* d_ws, size_t ws_size,
                              hipStream_t stream) {
    const float* f           = (const float*)d_in[0];
    const float* Minv        = (const float*)d_in[2];
    const float* actions     = (const float*)d_in[3];
    const float* inv_actions = (const float*)d_in[4];
    const float* w           = (const float*)d_in[6];
    const float* W1          = (const float*)d_in[7];
    const float* b1          = (const float*)d_in[8];
    const float* W2          = (const float*)d_in[9];
    const float* b2          = (const float*)d_in[10];
    const float* W3          = (const float*)d_in[11];
    const float* b3          = (const float*)d_in[12];
    float* outp = (float*)d_out;
    short* wsb = (short*)d_ws;
    float* wsf = (float*)d_ws;

    prep_kernel<<<1, 256, 0, stream>>>(actions, inv_actions, W1, b1, W2, W3, b3, wsb, wsf);
    lbm_kernel<<<NPIX / 256, 256, 0, stream>>>(f, Minv, w, b2, wsb, wsf, outp);
}

// Round 7
// 135.406 us; speedup vs baseline: 11.7334x; 1.0854x over previous
//
#include <hip/hip_runtime.h>
#include <hip/hip_bf16.h>
#include <math.h>

#define Q 9
#define NPIX (768 * 768)

typedef short bf16x8 __attribute__((ext_vector_type(8)));
typedef float f32x4 __attribute__((ext_vector_type(4)));
typedef int i32x4 __attribute__((ext_vector_type(4)));

// ws layout (shorts):
//   [0,4096)      A1a frags: 8 groups x 512   (W1e, m-half A, feature phiA(m)=8*(m>>2)+(m&3))
//   [4096,8192)   A1b frags: 8 groups x 512   (m-half B, phiB = phiA+4)
//   [8192,12288)  A3 frags:  8 groups x 512   (W3e, rows 0..2 used)
//   [12288,13312) A2a,A2b frags (W2)
// ws floats: b3t at float idx [6656,6659)
#define A1BV 512    // bf16x8-vector indices
#define A3V  1024
#define A2V  1536
#define B3TF 6656

__device__ __forceinline__ unsigned short f2bf(float x) {  // prep only
    unsigned u = __builtin_bit_cast(unsigned, x);
    unsigned r = u + 0x7FFFu + ((u >> 16) & 1u);
    return (unsigned short)(r >> 16);
}

// pack two f32 -> dword of two bf16 via v_cvt_pk_bf16_f32; first arg in LOW half
__device__ __forceinline__ unsigned pk2(float e, float o) {
    __hip_bfloat162 h = __float22bfloat162_rn(make_float2(e, o));
    unsigned u;
    __builtin_memcpy(&u, &h, 4);
    return u;
}

__device__ __forceinline__ bf16x8 mk8(unsigned w0, unsigned w1, unsigned w2, unsigned w3) {
    i32x4 t = {(int)w0, (int)w1, (int)w2, (int)w3};
    return __builtin_bit_cast(bf16x8, t);
}

// ---- prep: pack fused weights into per-lane 16x16x32 A-fragment order ----
// A-frag layout (HW-proven in R2): lane l holds A[m=l&15][k=(l>>4)*8+j], j=0..7.
// Parallel: one element per thread, 53 blocks x 256.
__global__ void prep_kernel(const float* __restrict__ actions,
                            const float* __restrict__ inv_actions,
                            const float* __restrict__ W1,
                            const float* __restrict__ b1,
                            const float* __restrict__ W2,
                            const float* __restrict__ W3,
                            const float* __restrict__ b3,
                            short* __restrict__ wsb,
                            float* __restrict__ wsf) {
    const int idx = blockIdx.x * 256 + threadIdx.x;
    if (idx < 8192) {
        // A1a / A1b: W1e[g][k][feat]; k<6: sum_i Ainv[g,i,k]*W1[i,feat]; k==6: b1; else 0
        int j = idx & 7, l = (idx >> 3) & 63, g = (idx >> 9) & 7, half = idx >> 12;
        int m = l & 15, quad = l >> 4, k = quad * 8 + j;
        int feat = 8 * (m >> 2) + (m & 3) + 4 * half;
        float v = 0.f;
        if (k < 6) {
            #pragma unroll
            for (int i = 0; i < 6; i++)
                v += inv_actions[g * 81 + i * 9 + k] * W1[i * 32 + feat];
        } else if (k == 6) v = b1[feat];
        wsb[idx] = (short)f2bf(v);
    } else if (idx < 12288) {
        // A3: W3e[g][k][m] = sum_j3 W3[k,j3]*A[g,6+m,6+j3], m<3 else 0
        int t = idx - 8192;
        int j = t & 7, l = (t >> 3) & 63, g = t >> 9;
        int m = l & 15, quad = l >> 4, k = quad * 8 + j;
        float v = 0.f;
        if (m < 3) {
            #pragma unroll
            for (int j3 = 0; j3 < 3; j3++)
                v += W3[k * 3 + j3] * actions[g * 81 + (6 + m) * 9 + (6 + j3)];
        }
        wsb[idx] = (short)f2bf(v);
    } else if (idx < 13312) {
        // A2a / A2b: W2[k][feat]
        int t = idx - 12288;
        int j = t & 7, l = (t >> 3) & 63, half = t >> 9;
        int m = l & 15, quad = l >> 4, k = quad * 8 + j;
        int feat = 8 * (m >> 2) + (m & 3) + 4 * half;
        wsb[idx] = (short)f2bf(W2[k * 32 + feat]);
    } else if (idx < 13315) {
        int t = idx - 13312;
        float acc = 0.f;
        for (int g = 0; g < 8; g++)
            #pragma unroll
            for (int j = 0; j < 3; j++)
                acc += actions[g * 81 + (6 + t) * 9 + (6 + j)] * b3[j];
        wsf[B3TF + t] = acc;
    }
}

__global__ __launch_bounds__(256, 4) void lbm_kernel(
    const float* __restrict__ f,
    const float* __restrict__ Minv,
    const float* __restrict__ w,
    const float* __restrict__ b2,
    const short* __restrict__ wsb,
    const float* __restrict__ wsf,
    float* __restrict__ out) {
    __shared__ float oL[4][64][4];

    const int tid = threadIdx.x;
    const int wv = tid >> 6;
    const int l = tid & 63;
    const int quad = l >> 4;
    const int lc = l & 15;
    const int p = blockIdx.x * 256 + tid;  // one pixel per lane

    // ---- load f, moments via {0,+-1} structure of M (19 adds) ----
    float fv0 = f[0 * NPIX + p], fv1 = f[1 * NPIX + p], fv2 = f[2 * NPIX + p];
    float fv3 = f[3 * NPIX + p], fv4 = f[4 * NPIX + p], fv5 = f[5 * NPIX + p];
    float fv6 = f[6 * NPIX + p], fv7 = f[7 * NPIX + p], fv8 = f[8 * NPIX + p];
    float sa = fv5 + fv6, sb = fv7 + fv8, sc = fv5 - fv6, sd = fv7 - fv8;
    float sab = sa + sb;
    float m8 = sab, m6 = sa - sb, m4 = sc + sd, m7 = sc - sd;
    float p13 = fv1 + fv3, d13 = fv1 - fv3, p24 = fv2 + fv4, d24 = fv2 - fv4;
    float m0 = fv0 + p13 + p24 + sab;
    float m1 = d13 + m7;
    float m2 = d24 + m6;
    float m3 = p13 + sab;
    float m5 = p24 + sab;

    // ---- B1 frags: broadcast moments of pixels nb*16..nb*16+15 to all quads ----
    unsigned mp0 = pk2(m0, m1), mp1 = pk2(m2, m3), mp2 = pk2(m4, m5);
    const unsigned CONE = 0x00003F80u;  // (bf16 1.0 at k=6, 0 at k=7)
    bf16x8 B1[4];
    #pragma unroll
    for (int nb = 0; nb < 4; nb++) {
        int src = ((nb << 4) | lc) << 2;
        unsigned a = (unsigned)__builtin_amdgcn_ds_bpermute(src, (int)mp0);
        unsigned b = (unsigned)__builtin_amdgcn_ds_bpermute(src, (int)mp1);
        unsigned c = (unsigned)__builtin_amdgcn_ds_bpermute(src, (int)mp2);
        B1[nb] = mk8(a, b, c, CONE);  // only quad-0 rows (k=0..7) have nonzero A1
    }

    // ---- resident weights ----
    const bf16x8* wsv = (const bf16x8*)wsb;
    bf16x8 a2a = wsv[A2V + l], a2b = wsv[A2V + 64 + l];
    f32x4 c2iA = *(const f32x4*)(b2 + 8 * quad);       // bias of features 8q..8q+3
    f32x4 c2iB = *(const f32x4*)(b2 + 8 * quad + 4);   // features 8q+4..8q+7
    float b30 = wsf[B3TF + 0], b31 = wsf[B3TF + 1], b32 = wsf[B3TF + 2];
    f32x4 oinit;
    oinit[0] = (quad == 0) ? b30 : 0.f;
    oinit[1] = (quad == 0) ? b31 : 0.f;
    oinit[2] = (quad == 0) ? b32 : 0.f;
    oinit[3] = 0.f;
    f32x4 oacc[4] = {oinit, oinit, oinit, oinit};

    bf16x8 a1a = wsv[l], a1b = wsv[A1BV + l], a3 = wsv[A3V + l];

    #pragma unroll 1
    for (int g = 0; g < 8; g++) {
        const int gn = (g + 1) & 7;  // cyclic prefetch (g=7 result unused)
        bf16x8 na1a = wsv[gn * 64 + l];
        bf16x8 na1b = wsv[A1BV + gn * 64 + l];
        bf16x8 na3  = wsv[A3V + gn * 64 + l];
        #pragma unroll
        for (int nb = 0; nb < 4; nb++) {
            f32x4 z = {0.f, 0.f, 0.f, 0.f};
            // layer 1: feature phiA(4q+r)=8q+r in c1a[r], phiB -> 8q+4+r in c1b[r]
            f32x4 c1a = __builtin_amdgcn_mfma_f32_16x16x32_bf16(a1a, B1[nb], z, 0, 0, 0);
            f32x4 c1b = __builtin_amdgcn_mfma_f32_16x16x32_bf16(a1b, B1[nb], z, 0, 0, 0);
            // purely lane-local C->B transform: quad q holds exactly k=8q..8q+7
            bf16x8 B2 = mk8(
                pk2(fmaxf(c1a[0], 0.f), fmaxf(c1a[1], 0.f)),
                pk2(fmaxf(c1a[2], 0.f), fmaxf(c1a[3], 0.f)),
                pk2(fmaxf(c1b[0], 0.f), fmaxf(c1b[1], 0.f)),
                pk2(fmaxf(c1b[2], 0.f), fmaxf(c1b[3], 0.f)));
            // layer 2 (bias via C-input)
            f32x4 c2a = __builtin_amdgcn_mfma_f32_16x16x32_bf16(a2a, B2, c2iA, 0, 0, 0);
            f32x4 c2b = __builtin_amdgcn_mfma_f32_16x16x32_bf16(a2b, B2, c2iB, 0, 0, 0);
            bf16x8 B3 = mk8(
                pk2(fmaxf(c2a[0], 0.f), fmaxf(c2a[1], 0.f)),
                pk2(fmaxf(c2a[2], 0.f), fmaxf(c2a[3], 0.f)),
                pk2(fmaxf(c2b[0], 0.f), fmaxf(c2b[1], 0.f)),
                pk2(fmaxf(c2b[2], 0.f), fmaxf(c2b[3], 0.f)));
            // layer 3: accumulate over groups in C (rows 0..2 = output components)
            oacc[nb] = __builtin_amdgcn_mfma_f32_16x16x32_bf16(a3, B3, oacc[nb], 0, 0, 0);
        }
        a1a = na1a; a1b = na1b; a3 = na3;
    }

    // ---- collect outputs: quad-0 lanes hold rows 0..3 (components) of cols 0..15 ----
    if (quad == 0) {
        #pragma unroll
        for (int nb = 0; nb < 4; nb++)
            *(f32x4*)&oL[wv][nb * 16 + lc][0] = oacc[nb];
    }
    // wave-local LDS RAW: in-order per wave, lgkmcnt wait inserted by compiler; no barrier
    f32x4 ov = *(const f32x4*)&oL[wv][l][0];
    float o_[3] = {ov[0], ov[1], ov[2]};  // b3t already folded into oacc init

    // ---- tau ----
    float tinv[3];
    #pragma unroll
    for (int i = 0; i < 3; i++) {
        float o = o_[i];
        float el = (o > 0.f) ? o : (__expf(o) - 1.f);
        tinv[i] = __builtin_amdgcn_rcpf(1.5f + el);
    }

    // ---- equilibrium (structured) ----
    float rho = m0;
    float ir = __builtin_amdgcn_rcpf(rho);
    float ux = m1 * ir, uy = m2 * ir;
    float usq = ux * ux + uy * uy;
    float base = 1.f - 1.5f * usq;
    float w0r = w[0] * rho, w1r = w[1] * rho, w5r = w[5] * rho;
    float feq0 = w0r * base;
    float ax = 4.5f * ux * ux + base, bx = 3.f * ux;
    float feq1 = w1r * (ax + bx), feq3 = w1r * (ax - bx);
    float ay = 4.5f * uy * uy + base, by = 3.f * uy;
    float feq2 = w1r * (ay + by), feq4 = w1r * (ay - by);
    float ss = ux + uy, as_ = 4.5f * ss * ss + base, bs = 3.f * ss;
    float feq5 = w5r * (as_ + bs), feq7 = w5r * (as_ - bs);
    float dd = uy - ux, ad = 4.5f * dd * dd + base, bd = 3.f * dd;
    float feq6 = w5r * (ad + bd), feq8 = w5r * (ad - bd);

    // meq = M @ feq (same 19-add structure)
    float ea = feq5 + feq6, eb = feq7 + feq8, ec = feq5 - feq6, ed = feq7 - feq8;
    float eab = ea + eb;
    float q8 = eab, q6 = ea - eb, q4 = ec + ed, q7 = ec - ed;
    float ep13 = feq1 + feq3, ed13 = feq1 - feq3, ep24 = feq2 + feq4, ed24 = feq2 - feq4;
    float q0 = feq0 + ep13 + ep24 + eab;
    float q1 = ed13 + q7, q2 = ed24 + q6, q3 = ep13 + eab, q5 = ep24 + eab;

    // relax
    float mp_[9];
    mp_[0] = m0 - (m0 - q0) * 1.25f;
    mp_[1] = m1 - (m1 - q1) * 1.25f;
    mp_[2] = m2 - (m2 - q2) * 1.25f;
    mp_[3] = m3 - (m3 - q3) * 1.25f;
    mp_[4] = m4 - (m4 - q4) * 1.25f;
    mp_[5] = m5 - (m5 - q5) * 1.25f;
    mp_[6] = m6 - (m6 - q6) * tinv[0];
    mp_[7] = m7 - (m7 - q7) * tinv[1];
    mp_[8] = m8 - (m8 - q8) * tinv[2];

    // out = Minv @ m_post (wave-uniform Minv -> scalar loads)
    #pragma unroll
    for (int q = 0; q < 9; q++) {
        float acc = Minv[q * 9 + 0] * mp_[0];
        #pragma unroll
        for (int pp = 1; pp < 9; pp++) acc = fmaf(Minv[q * 9 + pp], mp_[pp], acc);
        __builtin_nontemporal_store(acc, &out[q * NPIX + p]);
    }
}

extern "C" void kernel_launch(void* const* d_in, const int* in_sizes, int n_in,
                              void* d_out, int out_size, void* d_ws, size_t ws_size,
                              hipStream_t stream) {
    const float* f           = (const float*)d_in[0];
    const float* Minv        = (const float*)d_in[2];
    const float* actions     = (const float*)d_in[3];
    const float* inv_actions = (const float*)d_in[4];
    const float* w           = (const float*)d_in[6];
    const float* W1          = (const float*)d_in[7];
    const float* b1          = (const float*)d_in[8];
    const float* W2          = (const float*)d_in[9];
    const float* b2          = (const float*)d_in[10];
    const float* W3          = (const float*)d_in[11];
    const float* b3          = (const float*)d_in[12];
    float* outp = (float*)d_out;
    short* wsb = (short*)d_ws;
    float* wsf = (float*)d_ws;

    prep_kernel<<<53, 256, 0, stream>>>(actions, inv_actions, W1, b1, W2, W3, b3, wsb, wsf);
    lbm_kernel<<<NPIX / 256, 256, 0, stream>>>(f, Minv, w, b2, wsb, wsf, outp);
}